// Round 5
// baseline (347.129 us; speedup 1.0000x reference)
//
#include <hip/hip_runtime.h>
#include <math.h>

// Fastfood layer, round 8: software-pipelined m-loop + plain (cached) stores.
//
// Rounds 5-7 post-mortem: serial m-loop (345), ILP-2 (336), max-TLP (342)
// are all within +-1.5% -- occupancy 3->7 waves/SIMD changed NOTHING, so the
// limit is not latency capacity.  Pipe-sum model: VALU ~41us + LDS ~25us +
// L1/VMEM ~24us + HBM-write 43-130us ~= the observed ~165us kernel if the
// pipes do NOT overlap (phase-locked identical waves) and/or the nontemporal
// stores throttle write efficiency.  This round:
//   (1) cross-phase software pipelining inside each wave:
//       - B[m+1] prefetched across the loop back-edge (kills the serial
//         B-load -> x*B head of every iteration),
//       - P/G issued BEFORE FWHT#1 (~700cyc VALU cover vs ~100),
//       - S/u issued BEFORE FWHT#2,
//   (2) output stores are plain cached stores again (nt was added in round 5
//       and never isolated; output = 256MiB fits L3; wave stores are
//       full-line so no RFO penalty).
//
// FWHT-1024, all in registers (per wave):
//   bits 0-3 : reg-index butterflies
//   bits 4-7 : lane bits 0-3 via DPP (xor1=B1, xor2=4E, xor4=HMIR.1B, xor8=ror8)
//   bit 8    : v_permlane16_swap pair trick (swap, +/-, swap)
//   bit 9    : v_permlane32_swap pair trick
// LDS only for the permutation staging: 4x ds_write_b128 + 16 ds_read_b32
// per m.  Padding addr(i) = i + 4*(i>>6); per-wave private slices, no
// barriers.  FWHT#1 in natural layout (i = 16*lane + k); gather reads P/G at
// L2' positions (i' = 256*b + 4*lane + c) so FWHT#2 runs in the L2' layout
// (stages commute) and the epilogue is fully contiguous float4.

typedef unsigned uint2_ev __attribute__((ext_vector_type(2)));
typedef float    f32x4    __attribute__((ext_vector_type(4)));

template <int CTRL>
__device__ __forceinline__ float dpp_f(float x) {
    return __int_as_float(
        __builtin_amdgcn_mov_dpp(__float_as_int(x), CTRL, 0xF, 0xF, true));
}

#define DPP_XOR1 0xB1   // quad_perm [1,0,3,2]
#define DPP_XOR2 0x4E   // quad_perm [2,3,0,1]
#define DPP_XOR3 0x1B   // quad_perm [3,2,1,0]
#define DPP_HMIR 0x141  // row_half_mirror: lane ^ 7
#define DPP_ROR8 0x128  // row_ror:8 == lane ^ 8

// One permlane16_swap butterfly step on a register pair.
__device__ __forceinline__ void pl16_pair(float& e0, float& e1) {
    uint2_ev r = __builtin_amdgcn_permlane16_swap(
        __float_as_uint(e0), __float_as_uint(e1), false, false);
    float s = __uint_as_float(r.x) + __uint_as_float(r.y);
    float d = __uint_as_float(r.x) - __uint_as_float(r.y);
    uint2_ev q = __builtin_amdgcn_permlane16_swap(
        __float_as_uint(s), __float_as_uint(d), false, false);
    e0 = __uint_as_float(q.x);
    e1 = __uint_as_float(q.y);
}

__device__ __forceinline__ void pl32_pair(float& e0, float& e1) {
    uint2_ev r = __builtin_amdgcn_permlane32_swap(
        __float_as_uint(e0), __float_as_uint(e1), false, false);
    float s = __uint_as_float(r.x) + __uint_as_float(r.y);
    float d = __uint_as_float(r.x) - __uint_as_float(r.y);
    uint2_ev q = __builtin_amdgcn_permlane32_swap(
        __float_as_uint(s), __float_as_uint(d), false, false);
    e0 = __uint_as_float(q.x);
    e1 = __uint_as_float(q.y);
}

// Full 10-stage FWHT-1024, zero LDS traffic.
__device__ __forceinline__ void fwht_full(float v[16], float sg0, float sg1,
                                          float sg2, float sg3) {
    // reg-index bits (4 stages)
#pragma unroll
    for (int h = 1; h < 16; h <<= 1) {
#pragma unroll
        for (int k = 0; k < 16; ++k) {
            if (!(k & h)) {
                float a = v[k], b = v[k ^ h];
                v[k] = a + b;
                v[k ^ h] = a - b;
            }
        }
    }
    // lane bits 0-3 via DPP: new = partner + sg*v
#pragma unroll
    for (int k = 0; k < 16; ++k) v[k] = fmaf(v[k], sg0, dpp_f<DPP_XOR1>(v[k]));
#pragma unroll
    for (int k = 0; k < 16; ++k) v[k] = fmaf(v[k], sg1, dpp_f<DPP_XOR2>(v[k]));
#pragma unroll
    for (int k = 0; k < 16; ++k)
        v[k] = fmaf(v[k], sg2, dpp_f<DPP_XOR3>(dpp_f<DPP_HMIR>(v[k])));
#pragma unroll
    for (int k = 0; k < 16; ++k) v[k] = fmaf(v[k], sg3, dpp_f<DPP_ROR8>(v[k]));
    // lane bit 4 (lane ^ 16) and bit 5 (lane ^ 32): pair tricks
#pragma unroll
    for (int p = 0; p < 8; ++p) pl16_pair(v[2 * p], v[2 * p + 1]);
#pragma unroll
    for (int p = 0; p < 8; ++p) pl32_pair(v[2 * p], v[2 * p + 1]);
}

__global__ __launch_bounds__(256) void fastfood_kernel(
    const float* __restrict__ x, const float* __restrict__ B,
    const float* __restrict__ G, const float* __restrict__ S,
    const int* __restrict__ P, const float* __restrict__ u_rand,
    float* __restrict__ out)
{
    __shared__ float lds[4 * 1088];           // 4 waves * padded 1024
    const int lane = threadIdx.x & 63;
    const int wv   = threadIdx.x >> 6;
    const int row  = blockIdx.x * 4 + wv;

    const float sg0 = (lane & 1) ? -1.f : 1.f;
    const float sg1 = (lane & 2) ? -1.f : 1.f;
    const float sg2 = (lane & 4) ? -1.f : 1.f;
    const float sg3 = (lane & 8) ? -1.f : 1.f;

    float* wlds = lds + wv * 1088;
    // natural-layout padded write base: addr(16L+4j+c) = i + 4*(i>>6)
    float4* w4 = (float4*)(wlds + 16 * lane + 4 * (lane >> 2));

    const float c_arg = 0.03125f * 0.15915494309189535f;  // (1/32)*(1/2pi)
    const float c_amp = 0.015625f;                        // sqrt(2/8192)

    // Load x row once (natural layout, streamed -> nontemporal)
    float xv[16];
    {
        const f32x4* x4 = (const f32x4*)(x + (size_t)row * 1024 + 16 * lane);
#pragma unroll
        for (int j = 0; j < 4; ++j) {
            f32x4 t = __builtin_nontemporal_load(&x4[j]);
            xv[4 * j + 0] = t.x; xv[4 * j + 1] = t.y;
            xv[4 * j + 2] = t.z; xv[4 * j + 3] = t.w;
        }
    }

    // Cross-iteration B prefetch: load B[0] before the loop.
    float4 Bn0, Bn1, Bn2, Bn3;
    {
        const float4* B4 = (const float4*)(B + 16 * lane);
        Bn0 = B4[0]; Bn1 = B4[1]; Bn2 = B4[2]; Bn3 = B4[3];
    }

#pragma unroll 1
    for (int m = 0; m < 8; ++m) {
        const int mo = m << 10;

        // Consume prefetched B, immediately issue next iteration's B.
        float4 Bc0 = Bn0, Bc1 = Bn1, Bc2 = Bn2, Bc3 = Bn3;
        {
            const float4* Bq =
                (const float4*)(B + (m < 7 ? mo + 1024 : mo) + 16 * lane);
            Bn0 = Bq[0]; Bn1 = Bq[1]; Bn2 = Bq[2]; Bn3 = Bq[3];
        }

        float v[16];
        v[0]  = xv[0]  * Bc0.x; v[1]  = xv[1]  * Bc0.y;
        v[2]  = xv[2]  * Bc0.z; v[3]  = xv[3]  * Bc0.w;
        v[4]  = xv[4]  * Bc1.x; v[5]  = xv[5]  * Bc1.y;
        v[6]  = xv[6]  * Bc1.z; v[7]  = xv[7]  * Bc1.w;
        v[8]  = xv[8]  * Bc2.x; v[9]  = xv[9]  * Bc2.y;
        v[10] = xv[10] * Bc2.z; v[11] = xv[11] * Bc2.w;
        v[12] = xv[12] * Bc3.x; v[13] = xv[13] * Bc3.y;
        v[14] = xv[14] * Bc3.z; v[15] = xv[15] * Bc3.w;

        // Issue P/G now: ~700 cycles of FWHT#1 VALU cover their L2 latency.
        int4   pj[4];
        float4 gj[4];
        {
            const int4*   P4 = (const int4*)(P + mo);
            const float4* G4 = (const float4*)(G + mo);
#pragma unroll
            for (int j = 0; j < 4; ++j) {
                pj[j] = P4[64 * j + lane];
                gj[j] = G4[64 * j + lane];
            }
        }

        // ---- FWHT #1, fully in registers ----
        fwht_full(v, sg0, sg1, sg2, sg3);

        // Staging write for the gather (natural positions, 4x b128)
#pragma unroll
        for (int j = 0; j < 4; ++j)
            w4[j] = make_float4(v[4 * j + 0], v[4 * j + 1],
                                v[4 * j + 2], v[4 * j + 3]);

        // Issue S/u now: FWHT#2 covers their latency.
        float4 sv[4], uv[4];
        {
            const float4* S4 = (const float4*)(S + mo);
            const float4* U4 = (const float4*)(u_rand + mo);
#pragma unroll
            for (int b = 0; b < 4; ++b) {
                int idx = b * 64 + lane;
                sv[b] = S4[idx];
                uv[b] = U4[idx];
            }
        }

        // Random gather at L2' positions (i' = 256j + 4*lane + c) * G.
#pragma unroll
        for (int j = 0; j < 4; ++j) {
            int4 p = pj[j];
            float4 g = gj[j];
            v[4 * j + 0] = wlds[p.x + ((p.x >> 6) << 2)] * g.x;
            v[4 * j + 1] = wlds[p.y + ((p.y >> 6) << 2)] * g.y;
            v[4 * j + 2] = wlds[p.z + ((p.z >> 6) << 2)] * g.z;
            v[4 * j + 3] = wlds[p.w + ((p.w >> 6) << 2)] * g.w;
        }

        // ---- FWHT #2, fully in registers (L2' layout, stages commute) ----
        fwht_full(v, sg0, sg1, sg2, sg3);

        // Epilogue in L2': element i = b*256+4*lane+c -> float4 idx b*64+lane.
        // Plain cached stores (nt isolated out this round).
        {
            float4* o4 = (float4*)(out + (size_t)row * 8192 + mo);
#pragma unroll
            for (int b = 0; b < 4; ++b) {
                int idx = b * 64 + lane;
                float4 rr;
                rr.x = __builtin_amdgcn_cosf(__builtin_amdgcn_fractf(
                           fmaf(v[4 * b + 0] * sv[b].x, c_arg, uv[b].x))) * c_amp;
                rr.y = __builtin_amdgcn_cosf(__builtin_amdgcn_fractf(
                           fmaf(v[4 * b + 1] * sv[b].y, c_arg, uv[b].y))) * c_amp;
                rr.z = __builtin_amdgcn_cosf(__builtin_amdgcn_fractf(
                           fmaf(v[4 * b + 2] * sv[b].z, c_arg, uv[b].z))) * c_amp;
                rr.w = __builtin_amdgcn_cosf(__builtin_amdgcn_fractf(
                           fmaf(v[4 * b + 3] * sv[b].w, c_arg, uv[b].w))) * c_amp;
                o4[idx] = rr;
            }
        }
    }
}

extern "C" void kernel_launch(void* const* d_in, const int* in_sizes, int n_in,
                              void* d_out, int out_size, void* d_ws, size_t ws_size,
                              hipStream_t stream) {
    const float* x = (const float*)d_in[0];
    const float* B = (const float*)d_in[1];
    const float* G = (const float*)d_in[2];
    const float* S = (const float*)d_in[3];
    const int*   P = (const int*)d_in[4];
    const float* u = (const float*)d_in[5];
    float* out = (float*)d_out;

    dim3 grid(2048), block(256);
    hipLaunchKernelGGL(fastfood_kernel, grid, block, 0, stream,
                       x, B, G, S, P, u, out);
}

// Round 6
// 335.764 us; speedup vs baseline: 1.0338x; 1.0338x over previous
//
#include <hip/hip_runtime.h>
#include <math.h>

// Fastfood layer, round 9: RESTORE round-6 (best measured: 335.7 us).
//
// Series post-mortem: dur_us fits 326 + 15us/GB x (redundant table traffic).
//   r5 1-row m-loop        1.3 GB  -> 345.3
//   r6 2-row ILP-2         0.65GB  -> 335.7  (best)
//   r7 max-TLP             1.3 GB  -> 342.1
//   r8 SW-pipelined 1-row  1.3 GB  -> 347.1
// Scheduling levers (occupancy 3->7 w/SIMD, ILP, pipelining, nt vs plain
// stores) are all null; only table amortization moves the number, and its
// remaining headroom is <=10us.  The ~326us constant = harness fill ~167us
// (at 80% HBM peak, visible in top-5) + kernel <164us sitting at its
// no-overlap pipe-sum floor (VALU ~40 + LDS ~30 + L1 ~40 + HBM-write ~50).
// This round restores the measured optimum verbatim (2 rows per wave, one
// set of B/P/G/S/u loads per wave, interleaved ILP-2 chains, nt stores).
//
// FWHT-1024, all in registers (per row):
//   bits 0-3 : reg-index butterflies
//   bits 4-7 : lane bits 0-3 via DPP (xor1=B1, xor2=4E, xor4=HMIR.1B, xor8=ror8)
//   bit 8    : v_permlane16_swap pair trick (swap, +/-, swap)
//   bit 9    : v_permlane32_swap pair trick
// LDS only for the permutation staging: 4x ds_write_b128 + 16 ds_read_b32
// per row per m.  Padding addr(i) = i + 4*(i>>6) keeps b128 writes
// conflict-free; per-wave slices are private so no barriers are needed.

typedef unsigned uint2_ev __attribute__((ext_vector_type(2)));
typedef float    f32x4    __attribute__((ext_vector_type(4)));

template <int CTRL>
__device__ __forceinline__ float dpp_f(float x) {
    return __int_as_float(
        __builtin_amdgcn_mov_dpp(__float_as_int(x), CTRL, 0xF, 0xF, true));
}

#define DPP_XOR1 0xB1   // quad_perm [1,0,3,2]
#define DPP_XOR2 0x4E   // quad_perm [2,3,0,1]
#define DPP_XOR3 0x1B   // quad_perm [3,2,1,0]
#define DPP_HMIR 0x141  // row_half_mirror: lane ^ 7
#define DPP_ROR8 0x128  // row_ror:8 == lane ^ 8

// One permlane16_swap butterfly step on a register pair.
__device__ __forceinline__ void pl16_pair(float& e0, float& e1) {
    uint2_ev r = __builtin_amdgcn_permlane16_swap(
        __float_as_uint(e0), __float_as_uint(e1), false, false);
    float s = __uint_as_float(r.x) + __uint_as_float(r.y);
    float d = __uint_as_float(r.x) - __uint_as_float(r.y);
    uint2_ev q = __builtin_amdgcn_permlane16_swap(
        __float_as_uint(s), __float_as_uint(d), false, false);
    e0 = __uint_as_float(q.x);
    e1 = __uint_as_float(q.y);
}

__device__ __forceinline__ void pl32_pair(float& e0, float& e1) {
    uint2_ev r = __builtin_amdgcn_permlane32_swap(
        __float_as_uint(e0), __float_as_uint(e1), false, false);
    float s = __uint_as_float(r.x) + __uint_as_float(r.y);
    float d = __uint_as_float(r.x) - __uint_as_float(r.y);
    uint2_ev q = __builtin_amdgcn_permlane32_swap(
        __float_as_uint(s), __float_as_uint(d), false, false);
    e0 = __uint_as_float(q.x);
    e1 = __uint_as_float(q.y);
}

// Full 10-stage FWHT-1024 on TWO rows, interleaved for ILP.
__device__ __forceinline__ void fwht2(float a[16], float b[16], float sg0,
                                      float sg1, float sg2, float sg3) {
    // reg-index bits (4 stages)
#pragma unroll
    for (int h = 1; h < 16; h <<= 1) {
#pragma unroll
        for (int k = 0; k < 16; ++k) {
            if (!(k & h)) {
                float t0 = a[k], t1 = a[k ^ h];
                a[k] = t0 + t1;
                a[k ^ h] = t0 - t1;
                float u0 = b[k], u1 = b[k ^ h];
                b[k] = u0 + u1;
                b[k ^ h] = u0 - u1;
            }
        }
    }
    // lane bits 0-3 via DPP: new = partner + sg*v
#pragma unroll
    for (int k = 0; k < 16; ++k) {
        a[k] = fmaf(a[k], sg0, dpp_f<DPP_XOR1>(a[k]));
        b[k] = fmaf(b[k], sg0, dpp_f<DPP_XOR1>(b[k]));
    }
#pragma unroll
    for (int k = 0; k < 16; ++k) {
        a[k] = fmaf(a[k], sg1, dpp_f<DPP_XOR2>(a[k]));
        b[k] = fmaf(b[k], sg1, dpp_f<DPP_XOR2>(b[k]));
    }
#pragma unroll
    for (int k = 0; k < 16; ++k) {
        a[k] = fmaf(a[k], sg2, dpp_f<DPP_XOR3>(dpp_f<DPP_HMIR>(a[k])));
        b[k] = fmaf(b[k], sg2, dpp_f<DPP_XOR3>(dpp_f<DPP_HMIR>(b[k])));
    }
#pragma unroll
    for (int k = 0; k < 16; ++k) {
        a[k] = fmaf(a[k], sg3, dpp_f<DPP_ROR8>(a[k]));
        b[k] = fmaf(b[k], sg3, dpp_f<DPP_ROR8>(b[k]));
    }
    // lane bit 4 (lane ^ 16) and bit 5 (lane ^ 32): pair tricks
#pragma unroll
    for (int p = 0; p < 8; ++p) {
        pl16_pair(a[2 * p], a[2 * p + 1]);
        pl16_pair(b[2 * p], b[2 * p + 1]);
    }
#pragma unroll
    for (int p = 0; p < 8; ++p) {
        pl32_pair(a[2 * p], a[2 * p + 1]);
        pl32_pair(b[2 * p], b[2 * p + 1]);
    }
}

__global__ __launch_bounds__(256, 3) void fastfood_kernel(
    const float* __restrict__ x, const float* __restrict__ B,
    const float* __restrict__ G, const float* __restrict__ S,
    const int* __restrict__ P, const float* __restrict__ u_rand,
    float* __restrict__ out)
{
    __shared__ float lds[4 * 2176];           // 4 waves * 2 rows * padded 1024
    const int lane = threadIdx.x & 63;
    const int wv   = threadIdx.x >> 6;
    const int row  = blockIdx.x * 8 + wv * 2; // two consecutive rows per wave

    const float sg0 = (lane & 1) ? -1.f : 1.f;
    const float sg1 = (lane & 2) ? -1.f : 1.f;
    const float sg2 = (lane & 4) ? -1.f : 1.f;
    const float sg3 = (lane & 8) ? -1.f : 1.f;

    float* ldsA = lds + wv * 2176;
    float* ldsB = ldsA + 1088;
    // natural-layout padded write offset (all 16 of a lane's elements are
    // contiguous: pad only inserts at 64-element boundaries)
    const int woff = 16 * lane + 4 * (lane >> 2);
    float4* wA = (float4*)(ldsA + woff);
    float4* wB = (float4*)(ldsB + woff);

    const float c_arg = 0.03125f * 0.15915494309189535f;  // (1/32)*(1/2pi)
    const float c_amp = 0.015625f;                        // sqrt(2/8192)

    // Load both x rows once (natural layout, streamed -> nontemporal)
    float xvA[16], xvB[16];
    {
        const f32x4* xa = (const f32x4*)(x + (size_t)row * 1024 + 16 * lane);
        const f32x4* xb = (const f32x4*)(x + (size_t)(row + 1) * 1024 + 16 * lane);
#pragma unroll
        for (int j = 0; j < 4; ++j) {
            f32x4 t = __builtin_nontemporal_load(&xa[j]);
            xvA[4 * j + 0] = t.x; xvA[4 * j + 1] = t.y;
            xvA[4 * j + 2] = t.z; xvA[4 * j + 3] = t.w;
            f32x4 u = __builtin_nontemporal_load(&xb[j]);
            xvB[4 * j + 0] = u.x; xvB[4 * j + 1] = u.y;
            xvB[4 * j + 2] = u.z; xvB[4 * j + 3] = u.w;
        }
    }

#pragma unroll 1
    for (int m = 0; m < 8; ++m) {
        const int mo = m * 1024;
        float vA[16], vB[16];

        // v = x * B[m]  (natural layout; B loaded once, used for both rows)
        {
            const float4* B4 = (const float4*)(B + mo + 16 * lane);
#pragma unroll
            for (int j = 0; j < 4; ++j) {
                float4 bb = B4[j];
                vA[4 * j + 0] = xvA[4 * j + 0] * bb.x;
                vA[4 * j + 1] = xvA[4 * j + 1] * bb.y;
                vA[4 * j + 2] = xvA[4 * j + 2] * bb.z;
                vA[4 * j + 3] = xvA[4 * j + 3] * bb.w;
                vB[4 * j + 0] = xvB[4 * j + 0] * bb.x;
                vB[4 * j + 1] = xvB[4 * j + 1] * bb.y;
                vB[4 * j + 2] = xvB[4 * j + 2] * bb.z;
                vB[4 * j + 3] = xvB[4 * j + 3] * bb.w;
            }
        }

        // ---- FWHT #1, both rows, fully in registers ----
        fwht2(vA, vB, sg0, sg1, sg2, sg3);

        // P/G loads issued before the staging writes (independent; their
        // L2 latency overlaps the LDS round trip).  Loaded ONCE per wave.
        const int4*   P4 = (const int4*)(P + mo);
        const float4* G4 = (const float4*)(G + mo);
        int4   pj[4];
        float4 gj[4];
#pragma unroll
        for (int j = 0; j < 4; ++j) {
            pj[j] = P4[64 * j + lane];
            gj[j] = G4[64 * j + lane];
        }

        // Staging writes (natural positions, 4x b128 per row)
#pragma unroll
        for (int j = 0; j < 4; ++j) {
            wA[j] = make_float4(vA[4 * j + 0], vA[4 * j + 1],
                                vA[4 * j + 2], vA[4 * j + 3]);
            wB[j] = make_float4(vB[4 * j + 0], vB[4 * j + 1],
                                vB[4 * j + 2], vB[4 * j + 3]);
        }

        // Random gather at L2' positions (i' = 256j + 4*lane + c) * G.
        // Pad-offsets computed once, reused for both rows.
#pragma unroll
        for (int j = 0; j < 4; ++j) {
            int4 p = pj[j];
            float4 g = gj[j];
            int o0 = p.x + ((p.x >> 6) << 2);
            int o1 = p.y + ((p.y >> 6) << 2);
            int o2 = p.z + ((p.z >> 6) << 2);
            int o3 = p.w + ((p.w >> 6) << 2);
            vA[4 * j + 0] = ldsA[o0] * g.x;
            vA[4 * j + 1] = ldsA[o1] * g.y;
            vA[4 * j + 2] = ldsA[o2] * g.z;
            vA[4 * j + 3] = ldsA[o3] * g.w;
            vB[4 * j + 0] = ldsB[o0] * g.x;
            vB[4 * j + 1] = ldsB[o1] * g.y;
            vB[4 * j + 2] = ldsB[o2] * g.z;
            vB[4 * j + 3] = ldsB[o3] * g.w;
        }

        // ---- FWHT #2, both rows (L2' layout, stages commute) ----
        fwht2(vA, vB, sg0, sg1, sg2, sg3);

        // Epilogue in L2': element i = b*256 + 4*lane + c -> float4 idx b*64+lane
        // S/u loaded once, used for both rows.
        {
            const float4* S4 = (const float4*)(S + mo);
            const float4* U4 = (const float4*)(u_rand + mo);
            f32x4* oA = (f32x4*)(out + (size_t)row * 8192 + mo);
            f32x4* oB = (f32x4*)(out + (size_t)(row + 1) * 8192 + mo);
#pragma unroll
            for (int b = 0; b < 4; ++b) {
                int idx = b * 64 + lane;
                float4 sv = S4[idx], uv = U4[idx];
                f32x4 ra, rb;
                ra.x = __builtin_amdgcn_cosf(__builtin_amdgcn_fractf(
                           fmaf(vA[4 * b + 0] * sv.x, c_arg, uv.x))) * c_amp;
                ra.y = __builtin_amdgcn_cosf(__builtin_amdgcn_fractf(
                           fmaf(vA[4 * b + 1] * sv.y, c_arg, uv.y))) * c_amp;
                ra.z = __builtin_amdgcn_cosf(__builtin_amdgcn_fractf(
                           fmaf(vA[4 * b + 2] * sv.z, c_arg, uv.z))) * c_amp;
                ra.w = __builtin_amdgcn_cosf(__builtin_amdgcn_fractf(
                           fmaf(vA[4 * b + 3] * sv.w, c_arg, uv.w))) * c_amp;
                rb.x = __builtin_amdgcn_cosf(__builtin_amdgcn_fractf(
                           fmaf(vB[4 * b + 0] * sv.x, c_arg, uv.x))) * c_amp;
                rb.y = __builtin_amdgcn_cosf(__builtin_amdgcn_fractf(
                           fmaf(vB[4 * b + 1] * sv.y, c_arg, uv.y))) * c_amp;
                rb.z = __builtin_amdgcn_cosf(__builtin_amdgcn_fractf(
                           fmaf(vB[4 * b + 2] * sv.z, c_arg, uv.z))) * c_amp;
                rb.w = __builtin_amdgcn_cosf(__builtin_amdgcn_fractf(
                           fmaf(vB[4 * b + 3] * sv.w, c_arg, uv.w))) * c_amp;
                __builtin_nontemporal_store(ra, &oA[idx]);
                __builtin_nontemporal_store(rb, &oB[idx]);
            }
        }
    }
}

extern "C" void kernel_launch(void* const* d_in, const int* in_sizes, int n_in,
                              void* d_out, int out_size, void* d_ws, size_t ws_size,
                              hipStream_t stream) {
    const float* x = (const float*)d_in[0];
    const float* B = (const float*)d_in[1];
    const float* G = (const float*)d_in[2];
    const float* S = (const float*)d_in[3];
    const int*   P = (const int*)d_in[4];
    const float* u = (const float*)d_in[5];
    float* out = (float*)d_out;

    dim3 grid(1024), block(256);
    hipLaunchKernelGGL(fastfood_kernel, grid, block, 0, stream,
                       x, B, G, S, P, u, out);
}